// Round 10
// baseline (152.920 us; speedup 1.0000x reference)
//
#include <hip/hip_runtime.h>
#include <hip/hip_bf16.h>
#include <stdint.h>

#define BATCH   65536
#define UNITS   256
#define NCHUNK  8
#define ROWP    72                     // shorts per column in gate buffer (16B-aligned, read-conflict-free)
#define GSZ     (64 * ROWP)            // 4608 shorts per gate
#define SMEM_BYTES 65536               // A-tile 64 rows x 512 k bf16 (G 36864 reuses it)

using f32x16 = __attribute__((ext_vector_type(16))) float;
using bf16x8 = __attribute__((ext_vector_type(8))) short;

__device__ __forceinline__ short f2bf(float f) {
  union { float f; unsigned u; } v; v.f = f;
  unsigned r = v.u + 0x7FFFu + ((v.u >> 16) & 1u);   // RNE (prepass only)
  return (short)(r >> 16);
}
__device__ __forceinline__ float bf2f(short s) {
  union { float f; unsigned u; } v; v.u = ((unsigned)(unsigned short)s) << 16;
  return v.f;
}
__device__ __forceinline__ unsigned pk2(float a, float b) {   // v_cvt_pk_bf16_f32
  union { __hip_bfloat162 h; unsigned u; } cv;
  cv.h = __float22bfloat162_rn(make_float2(a, b));
  return cv.u;
}

#define BAR() do { asm volatile("s_waitcnt lgkmcnt(0)" ::: "memory"); \
                   __builtin_amdgcn_s_barrier(); } while (0)

// ---- prepass: W_g fp32 [512][256] -> Wt bf16 tiled [g][nb][c][kg][n][k8]
__global__ void cvt_weights(const float* __restrict__ Wf, const float* __restrict__ Wi,
                            const float* __restrict__ Wc, const float* __restrict__ Wo,
                            short* __restrict__ Wt) {
  int idx = blockIdx.x * 256 + threadIdx.x;
  int g   = idx >> 17;
  int k   = (idx >> 8) & 511;
  int col = idx & 255;
  const float* W = (g == 0) ? Wf : (g == 1) ? Wi : (g == 2) ? Wc : Wo;
  float val = W[k * 256 + col];
  int nb = col >> 6, n = col & 63;
  int c = k >> 6, kg = (k >> 3) & 7, k8 = k & 7;
  int out = ((((g * 4 + nb) * 8 + c) * 8 + kg) * 64 + n) * 8 + k8;
  Wt[out] = f2bf(val);
}

// ---- fused LSTM cell: stage the ENTIRE 64x512 A-tile (bf16, kg-XOR-swizzled)
// in LDS once, then a barrier-free K loop: 4 waves (one per gate), A-frags from
// LDS, B reg-double-buffered from L2 (pre-tiled Wt). 3 barriers total.
__global__ __launch_bounds__(256, 2) void lstm_fused(
    const float* __restrict__ x, const float* __restrict__ hprev,
    const float* __restrict__ cprev, const short* __restrict__ Wt,
    const float* __restrict__ bfp, const float* __restrict__ bip,
    const float* __restrict__ bcp, const float* __restrict__ bop,
    float* __restrict__ hout, float* __restrict__ cout)
{
  extern __shared__ __align__(16) char smem[];
  const int tid  = threadIdx.x;
  const int g    = tid >> 6;           // wave = gate
  const int lane = tid & 63;
  const int la   = lane & 31;
  const int hh   = lane >> 5;

  int bid = blockIdx.x;
  int wg  = (bid & 7) * 512 + (bid >> 3);      // XCD-bijective swizzle
  const int m0 = (wg >> 2) * 64;
  const int nb = wg & 3;
  const int n0 = nb * 64;

  const short* Bbase = Wt + ((size_t)(g * 4 + nb)) * 32768 + hh * 512 + la * 8;

  f32x16 acc[2][2] = {};
  bf16x8 bregA[8], bregB[8];

  auto loadB = [&](int c, bf16x8* br) {
#pragma unroll
    for (int ks = 0; ks < 4; ++ks) {
      const short* Bc = Bbase + (size_t)c * 4096 + ks * 1024;
      br[2 * ks]     = *(const bf16x8*)(Bc);
      br[2 * ks + 1] = *(const bf16x8*)(Bc + 256);
    }
  };
  auto compute = [&](int c, const bf16x8* br) {
#pragma unroll
    for (int ks = 0; ks < 4; ++ks) {
      const int kg  = c * 8 + 2 * ks + hh;
      const int off = kg * 1024 + ((la * 16) ^ ((kg & 7) << 4));
      bf16x8 a0 = *(const bf16x8*)(smem + off);
      bf16x8 a1 = *(const bf16x8*)(smem + off + 512);   // row +32: bit9 untouched by swz
      acc[0][0] = __builtin_amdgcn_mfma_f32_32x32x16_bf16(a0, br[2*ks],   acc[0][0], 0, 0, 0);
      acc[0][1] = __builtin_amdgcn_mfma_f32_32x32x16_bf16(a0, br[2*ks+1], acc[0][1], 0, 0, 0);
      acc[1][0] = __builtin_amdgcn_mfma_f32_32x32x16_bf16(a1, br[2*ks],   acc[1][0], 0, 0, 0);
      acc[1][1] = __builtin_amdgcn_mfma_f32_32x32x16_bf16(a1, br[2*ks+1], acc[1][1], 0, 0, 0);
    }
  };

  // ---- stage full A-tile: x-tile and h-tile are each contiguous 64 KB ----
  loadB(0, bregA);                               // B(0): oldest in FIFO (L2)
  {
    const float4* xt = (const float4*)(x     + (size_t)m0 * 256);
    const float4* ht = (const float4*)(hprev + (size_t)m0 * 256);
    float4 vx[16], vh[16];
#pragma unroll
    for (int i = 0; i < 16; ++i) vx[i] = xt[tid + 256 * i];
#pragma unroll
    for (int i = 0; i < 16; ++i) vh[i] = ht[tid + 256 * i];
#pragma unroll
    for (int i = 0; i < 16; ++i) {
      const int idx = tid + 256 * i;             // float4 index in 64x256 tile
      const int row = idx >> 6, k4 = idx & 63;
      const int kg = k4 >> 1, half = k4 & 1;
      const int sub = (row * 16 + half * 8) ^ ((kg & 7) << 4);   // XOR swizzle
      uint2 ux; ux.x = pk2(vx[i].x, vx[i].y); ux.y = pk2(vx[i].z, vx[i].w);
      *(uint2*)(smem + kg * 1024 + sub) = ux;
      uint2 uh; uh.x = pk2(vh[i].x, vh[i].y); uh.y = pk2(vh[i].z, vh[i].w);
      *(uint2*)(smem + (kg + 32) * 1024 + sub) = uh;
    }
  }
  BAR();                                         // #1: A-tile ready

  // ---- barrier-free K loop: B reg-dbuf prefetched one chunk ahead ----
#pragma unroll
  for (int c = 0; c < NCHUNK; ++c) {
    bf16x8* cur = (c & 1) ? bregB : bregA;
    bf16x8* nxt = (c & 1) ? bregA : bregB;
    if (c + 1 < NCHUNK) loadB(c + 1, nxt);
    __builtin_amdgcn_s_setprio(1);
    compute(c, cur);
    __builtin_amdgcn_s_setprio(0);
  }

  // ---- epilogue ----
  const int ccol = tid & 63;
  const int rg   = tid >> 6;
  const size_t gbase = (size_t)(m0 + rg * 16) * 256 + n0 + ccol;
  float cp[16];
#pragma unroll
  for (int j = 0; j < 16; ++j) cp[j] = cprev[gbase + (size_t)j * 256];
  BAR();                                         // #2: all A reads done, reuse LDS as G

  const float* bptr = (g == 0) ? bfp : (g == 1) ? bip : (g == 2) ? bcp : bop;
  const float bias0 = bptr[n0 + la];
  const float bias1 = bptr[n0 + 32 + la];
  short* G = (short*)smem;
#pragma unroll
  for (int mi = 0; mi < 2; ++mi)
#pragma unroll
    for (int ni = 0; ni < 2; ++ni) {
      const float bias = ni ? bias1 : bias0;
      const int   col  = la + ni * 32;
#pragma unroll
      for (int rq = 0; rq < 4; ++rq) {
        const int row0 = rq * 8 + 4 * hh + mi * 32;
        float t[4];
#pragma unroll
        for (int e = 0; e < 4; ++e) {
          float vv = acc[mi][ni][rq * 4 + e] + bias;
          t[e] = (g == 2) ? (1.f - 2.f / (__expf(2.f * vv) + 1.f))   // tanh
                          : (1.f / (1.f + __expf(-vv)));             // sigmoid
        }
        uint2 u; u.x = pk2(t[0], t[1]); u.y = pk2(t[2], t[3]);
        *(uint2*)(G + g * GSZ + col * ROWP + row0) = u;
      }
    }
  BAR();                                         // #3: gates exchanged

  // ---- combine + store: thread -> col = tid&63, rows rg*16..+15 ----
  {
    const short* Gp = G + ccol * ROWP + rg * 16;
    bf16x8 gf[4][2];
#pragma unroll
    for (int gg = 0; gg < 4; ++gg) {
      gf[gg][0] = *(const bf16x8*)(Gp + gg * GSZ);
      gf[gg][1] = *(const bf16x8*)(Gp + gg * GSZ + 8);
    }
#pragma unroll
    for (int j = 0; j < 16; ++j) {
      float fg = bf2f(gf[0][j >> 3][j & 7]);
      float ig = bf2f(gf[1][j >> 3][j & 7]);
      float cg = bf2f(gf[2][j >> 3][j & 7]);
      float og = bf2f(gf[3][j >> 3][j & 7]);
      float cnew = fg * cp[j] + ig * cg;
      float hnew = og * (1.f - 2.f / (__expf(2.f * cnew) + 1.f));
      hout[gbase + (size_t)j * 256] = hnew;
      cout[gbase + (size_t)j * 256] = cnew;
    }
  }
}

extern "C" void kernel_launch(void* const* d_in, const int* in_sizes, int n_in,
                              void* d_out, int out_size, void* d_ws, size_t ws_size,
                              hipStream_t stream) {
  const float* x     = (const float*)d_in[0];
  const float* hprev = (const float*)d_in[1];
  const float* cprev = (const float*)d_in[2];
  const float* Wf    = (const float*)d_in[3];
  const float* Wi    = (const float*)d_in[4];
  const float* Wc    = (const float*)d_in[5];
  const float* Wo    = (const float*)d_in[6];
  const float* bfp   = (const float*)d_in[7];
  const float* bip   = (const float*)d_in[8];
  const float* bcp   = (const float*)d_in[9];
  const float* bop   = (const float*)d_in[10];
  float* out = (float*)d_out;
  short* Wt  = (short*)d_ws;     // 1 MB scratch

  cvt_weights<<<2048, 256, 0, stream>>>(Wf, Wi, Wc, Wo, Wt);

  lstm_fused<<<dim3(4096), dim3(256), SMEM_BYTES, stream>>>(
      x, hprev, cprev, Wt, bfp, bip, bcp, bop,
      out, out + (size_t)BATCH * UNITS);
}